// Round 3
// baseline (1116.187 us; speedup 1.0000x reference)
//
#include <hip/hip_runtime.h>
#include <hip/hip_bf16.h>

#define N_NODES   50000
#define EDGES     1600000
#define D         128
#define K_INC     2000
#define K_TOT     2128   // 2000 (inc) + 128 (curr_h)
#define K_PAD     2176   // padded to multiple of 32
#define LN_EPS    1e-5f

typedef float f32x4 __attribute__((ext_vector_type(4)));
typedef short short8 __attribute__((ext_vector_type(8)));   // 8 bf16 lanes (guide-verified MFMA operand type)

// ---------------- index-width probe: flag=1 if src looks like raw int64 ----------------
__global__ void probe_kernel(const int* __restrict__ src, int* __restrict__ flag) {
    __shared__ int any_nonzero;
    if (threadIdx.x == 0) any_nonzero = 0;
    __syncthreads();
    int v = src[threadIdx.x * 2 + 1];   // odd 32-bit words: all-zero iff little-endian int64 with vals < 2^31
    if (v != 0) any_nonzero = 1;        // benign race
    __syncthreads();
    if (threadIdx.x == 0) flag[0] = any_nonzero ? 0 : 1;
}

// ---------------- zero fill ----------------
__global__ void zero_kernel(int* __restrict__ p, int n) {
    int i = blockIdx.x * 256 + threadIdx.x;
    if (i < n) p[i] = 0;
}

// ---------------- degree histogram ----------------
__global__ void deg_kernel(const int* __restrict__ src, const int* __restrict__ dst,
                           const int* __restrict__ flag,
                           int* __restrict__ out_deg, int* __restrict__ in_cnt) {
    int e = blockIdx.x * 256 + threadIdx.x;
    int st = 1 + flag[0];
    if (e < EDGES) {
        atomicAdd(&out_deg[src[e * st]], 1);
        atomicAdd(&in_cnt[dst[e * st]], 1);
    }
}

// ---------------- one-block chunked exclusive scan over N ----------------
__global__ __launch_bounds__(1024) void scan_kernel(const int* __restrict__ cnt,
                                                    int* __restrict__ row_start) {
    __shared__ int buf[1024];
    int t = threadIdx.x;
    const int N = N_NODES;
    int chunk = (N + 1023) / 1024;
    int lo = t * chunk, hi = min(lo + chunk, N);
    int s = 0;
    for (int i = lo; i < hi; ++i) s += cnt[i];
    buf[t] = s;
    __syncthreads();
    for (int off = 1; off < 1024; off <<= 1) {
        int v = (t >= off) ? buf[t - off] : 0;
        __syncthreads();
        buf[t] += v;
        __syncthreads();
    }
    int run = (t > 0) ? buf[t - 1] : 0;
    for (int i = lo; i < hi; ++i) { row_start[i] = run; run += cnt[i]; }
    if (t == 1023) row_start[N] = buf[1023];
}

// ---------------- CSR scatter (dst-sorted src list) ----------------
__global__ void fill_kernel(const int* __restrict__ src, const int* __restrict__ dst,
                            const int* __restrict__ flag,
                            const int* __restrict__ row_start, int* __restrict__ cursor,
                            int* __restrict__ csr_src) {
    int e = blockIdx.x * 256 + threadIdx.x;
    int st = 1 + flag[0];
    if (e < EDGES) {
        int d = dst[e * st];
        int pos = atomicAdd(&cursor[d], 1);
        csr_src[row_start[d] + pos] = src[e * st];
    }
}

// ---------------- PbT[n][k] (bf16): rows k<K_INC hold (next_h @ (W_fus .* topDown_w))^T;
// ---------------- rows K_INC..K_TOT hold (W_conv .* conv_w)^T; rest zero ----------------
__global__ __launch_bounds__(128) void p_kernel(
    const float* __restrict__ next_h, const float* __restrict__ W_fus,
    const float* __restrict__ topDown_w, const float* __restrict__ W_conv,
    const float* __restrict__ conv_w, __hip_bfloat16* __restrict__ PbT) {
    int k = blockIdx.x, n = threadIdx.x;
    float v;
    if (k < K_INC) {
        __shared__ float nh[D];
        nh[n] = next_h[k * D + n];
        __syncthreads();
        float acc = 0.f;
        for (int j = 0; j < D; ++j) acc += nh[j] * W_fus[j * D + n];
        v = acc * topDown_w[n];
    } else if (k < K_TOT) {
        v = W_conv[(k - K_INC) * D + n] * conv_w[n];
    } else {
        v = 0.f;
    }
    PbT[(size_t)n * K_PAD + k] = __float2bfloat16(v);
}

// ---------------- big GEMM: Zs = ([inc | curr_h] @ PbT^T) * norm_out ----------------
// 256 threads (4 waves as 2x2 of 64x64 wave-tiles), block tile 128x128, BK=32
__global__ __launch_bounds__(256) void gemm_kernel(
    const float* __restrict__ inc, const float* __restrict__ curr_h,
    const ushort* __restrict__ PbT, const int* __restrict__ out_deg,
    float* __restrict__ Zs) {
    __shared__ ushort As[128][40];   // [m][k] bf16, 32 payload + 8 pad
    __shared__ ushort Bs[128][40];   // [n][k] bf16
    const int N = N_NODES;
    int tid = threadIdx.x;
    int wave = tid >> 6, lane = tid & 63;
    int wm = wave >> 1, wn = wave & 1;
    int r = lane & 15, q = lane >> 4;
    int rowBase = blockIdx.x * 128;

    f32x4 acc[4][4] = {};

    for (int kt = 0; kt < K_PAD / 32; ++kt) {
        int k0 = kt * 32;
        __syncthreads();
        // ---- stage A: 128 rows x 32 f32 -> bf16 LDS. 1024 float4 chunks, 4 per thread ----
#pragma unroll
        for (int it = 0; it < 4; ++it) {
            int id = tid + it * 256;           // 0..1023
            int arow = id >> 3, q4 = id & 7;   // row 0..127, 4-float chunk 0..7
            int gk = k0 + q4 * 4;
            int grow = rowBase + arow; if (grow >= N) grow = N - 1;
            float4 va;
            if (gk < K_INC)      va = *(const float4*)(inc + (size_t)grow * K_INC + gk);
            else if (gk < K_TOT) va = *(const float4*)(curr_h + (size_t)grow * D + (gk - K_INC));
            else                 va = make_float4(0.f, 0.f, 0.f, 0.f);
            ushort4 hb;
            hb.x = __hip_bfloat16_raw(__float2bfloat16(va.x)).x;
            hb.y = __hip_bfloat16_raw(__float2bfloat16(va.y)).x;
            hb.z = __hip_bfloat16_raw(__float2bfloat16(va.z)).x;
            hb.w = __hip_bfloat16_raw(__float2bfloat16(va.w)).x;
            *(ushort4*)&As[arow][q4 * 4] = hb;
        }
        // ---- stage B: 128 rows x 32 bf16. 512 uint4 chunks, 2 per thread ----
#pragma unroll
        for (int it = 0; it < 2; ++it) {
            int id = tid + it * 256;           // 0..511
            int brow = id >> 2, qc = id & 3;   // row 0..127, 8-bf16 chunk 0..3
            uint4 vb = *(const uint4*)(PbT + (size_t)brow * K_PAD + k0 + qc * 8);
            *(uint4*)&Bs[brow][qc * 8] = vb;
        }
        __syncthreads();
        short8 af[4], bfr[4];
#pragma unroll
        for (int mi = 0; mi < 4; ++mi) af[mi] = *(const short8*)&As[wm * 64 + mi * 16 + r][q * 8];
#pragma unroll
        for (int ni = 0; ni < 4; ++ni) bfr[ni] = *(const short8*)&Bs[wn * 64 + ni * 16 + r][q * 8];
#pragma unroll
        for (int mi = 0; mi < 4; ++mi)
#pragma unroll
            for (int ni = 0; ni < 4; ++ni)
                acc[mi][ni] = __builtin_amdgcn_mfma_f32_16x16x32_bf16(af[mi], bfr[ni], acc[mi][ni], 0, 0, 0);
    }

#pragma unroll
    for (int mi = 0; mi < 4; ++mi) {
#pragma unroll
        for (int j = 0; j < 4; ++j) {
            int grow = rowBase + wm * 64 + mi * 16 + q * 4 + j;   // C/D: row = (lane>>4)*4 + reg  [m89]
            if (grow < N) {
                float no = rsqrtf((float)(out_deg[grow] + 1));    // +1 self-loop
#pragma unroll
                for (int ni = 0; ni < 4; ++ni) {
                    int col = wn * 64 + ni * 16 + r;              // C/D: col = lane&15  [m89]
                    Zs[(size_t)grow * D + col] = acc[mi][ni][j] * no;
                }
            }
        }
    }
}

// ---------------- fused aggregation + norm_in + bias + LayerNorm + ReLU ----------------
__global__ __launch_bounds__(128) void agg_ln_kernel(
    const float* __restrict__ Zs, const int* __restrict__ row_start,
    const int* __restrict__ csr_src,
    const float* __restrict__ b_conv, const float* __restrict__ b_fus,
    const float* __restrict__ conv_w, const float* __restrict__ topDown_w,
    const float* __restrict__ gamma, const float* __restrict__ beta,
    float* __restrict__ out) {
    int i = blockIdx.x, c = threadIdx.x;
    float acc = Zs[(size_t)i * D + c];          // self-loop
    int beg = row_start[i], end = row_start[i + 1];
    for (int e = beg; e < end; ++e) {
        int s = csr_src[e];
        acc += Zs[(size_t)s * D + c];
    }
    float norm_in = rsqrtf((float)(end - beg + 1));
    float cv = b_conv[c] * conv_w[c] + b_fus[c] * topDown_w[c];
    float y = acc * norm_in + cv;

    // LayerNorm over 128 channels (2 waves)
    float s1 = y, s2 = y * y;
#pragma unroll
    for (int off = 32; off > 0; off >>= 1) {
        s1 += __shfl_down(s1, off);
        s2 += __shfl_down(s2, off);
    }
    __shared__ float sh[4];
    int wid = threadIdx.x >> 6;
    if ((threadIdx.x & 63) == 0) { sh[wid * 2] = s1; sh[wid * 2 + 1] = s2; }
    __syncthreads();
    float S = sh[0] + sh[2], SS = sh[1] + sh[3];
    float mu = S * (1.f / D);
    float var = SS * (1.f / D) - mu * mu;
    float rstd = rsqrtf(var + LN_EPS);
    float rv = (y - mu) * rstd * gamma[c] + beta[c];
    out[(size_t)i * D + c] = fmaxf(rv, 0.f);
}

extern "C" void kernel_launch(void* const* d_in, const int* in_sizes, int n_in,
                              void* d_out, int out_size, void* d_ws, size_t ws_size,
                              hipStream_t stream) {
    const float* curr_h    = (const float*)d_in[0];
    const float* next_h    = (const float*)d_in[1];
    const float* inc       = (const float*)d_in[2];
    const int*   src       = (const int*)d_in[3];
    const int*   dst       = (const int*)d_in[4];
    const float* W_conv    = (const float*)d_in[5];
    const float* b_conv    = (const float*)d_in[6];
    const float* W_fus     = (const float*)d_in[7];
    const float* b_fus     = (const float*)d_in[8];
    const float* conv_w    = (const float*)d_in[9];
    const float* topDown_w = (const float*)d_in[10];
    const float* ln_gamma  = (const float*)d_in[11];
    const float* ln_beta   = (const float*)d_in[12];

    const int N = N_NODES;
    const int E = EDGES;

    // ---- workspace carve ----
    char* p = (char*)d_ws;
    float* Zs = (float*)p;                    p += (size_t)N * D * sizeof(float);   // 25.6 MB
    __hip_bfloat16* PbT = (__hip_bfloat16*)p; p += (size_t)D * K_PAD * 2;           // 557 KB
    int* out_deg   = (int*)p;                 p += (size_t)N * 4;                   // contiguous:
    int* in_cnt    = (int*)p;                 p += (size_t)N * 4;                   //   out_deg, in_cnt, cursor
    int* cursor    = (int*)p;                 p += (size_t)N * 4;
    int* row_start = (int*)p;                 p += (size_t)(N + 1) * 4;
    int* idx_flag  = (int*)p;                 p += 256;
    int* csr_src   = (int*)p;                 p += (size_t)E * 4;

    probe_kernel<<<1, 1024, 0, stream>>>(src, idx_flag);
    zero_kernel<<<(3 * N + 255) / 256, 256, 0, stream>>>(out_deg, 3 * N);
    deg_kernel<<<(E + 255) / 256, 256, 0, stream>>>(src, dst, idx_flag, out_deg, in_cnt);
    scan_kernel<<<1, 1024, 0, stream>>>(in_cnt, row_start);
    fill_kernel<<<(E + 255) / 256, 256, 0, stream>>>(src, dst, idx_flag, row_start, cursor, csr_src);
    p_kernel<<<K_PAD, 128, 0, stream>>>(next_h, W_fus, topDown_w, W_conv, conv_w, PbT);
    gemm_kernel<<<(N + 127) / 128, 256, 0, stream>>>(inc, curr_h, (const ushort*)PbT, out_deg, Zs);
    agg_ln_kernel<<<N, 128, 0, stream>>>(Zs, row_start, csr_src,
                                         b_conv, b_fus, conv_w, topDown_w,
                                         ln_gamma, ln_beta, (float*)d_out);
}

// Round 4
// 982.615 us; speedup vs baseline: 1.1359x; 1.1359x over previous
//
#include <hip/hip_runtime.h>
#include <hip/hip_bf16.h>

#define N_NODES   50000
#define EDGES     1600000
#define D         128
#define K_INC     2000
#define K_TOT     2128   // 2000 (inc) + 128 (curr_h)
#define K_PAD     2176   // padded to multiple of 64 (34 * 64)
#define LN_EPS    1e-5f

typedef float f32x4 __attribute__((ext_vector_type(4)));
typedef short short8 __attribute__((ext_vector_type(8)));   // 8 bf16 lanes (MFMA operand)

__device__ __forceinline__ ushort f2bf(float x) {
    return __hip_bfloat16_raw(__float2bfloat16(x)).x;
}
__device__ __forceinline__ float bf_lo(uint v) { return __uint_as_float(v << 16); }
__device__ __forceinline__ float bf_hi(uint v) { return __uint_as_float(v & 0xffff0000u); }

// ---------------- index-width probe: flag=1 if src looks like raw int64 ----------------
__global__ void probe_kernel(const int* __restrict__ src, int* __restrict__ flag) {
    __shared__ int any_nonzero;
    if (threadIdx.x == 0) any_nonzero = 0;
    __syncthreads();
    int v = src[threadIdx.x * 2 + 1];   // odd words all-zero iff little-endian int64, vals < 2^31
    if (v != 0) any_nonzero = 1;
    __syncthreads();
    if (threadIdx.x == 0) flag[0] = any_nonzero ? 0 : 1;
}

// ---------------- zero fill ----------------
__global__ void zero_kernel(int* __restrict__ p, int n) {
    int i = blockIdx.x * 256 + threadIdx.x;
    if (i < n) p[i] = 0;
}

// ---------------- degree histogram ----------------
__global__ void deg_kernel(const int* __restrict__ src, const int* __restrict__ dst,
                           const int* __restrict__ flag,
                           int* __restrict__ out_deg, int* __restrict__ in_cnt) {
    int e = blockIdx.x * 256 + threadIdx.x;
    int st = 1 + flag[0];
    if (e < EDGES) {
        atomicAdd(&out_deg[src[e * st]], 1);
        atomicAdd(&in_cnt[dst[e * st]], 1);
    }
}

// ---------------- one-block chunked exclusive scan over N ----------------
__global__ __launch_bounds__(1024) void scan_kernel(const int* __restrict__ cnt,
                                                    int* __restrict__ row_start) {
    __shared__ int buf[1024];
    int t = threadIdx.x;
    const int N = N_NODES;
    int chunk = (N + 1023) / 1024;
    int lo = t * chunk, hi = min(lo + chunk, N);
    int s = 0;
    for (int i = lo; i < hi; ++i) s += cnt[i];
    buf[t] = s;
    __syncthreads();
    for (int off = 1; off < 1024; off <<= 1) {
        int v = (t >= off) ? buf[t - off] : 0;
        __syncthreads();
        buf[t] += v;
        __syncthreads();
    }
    int run = (t > 0) ? buf[t - 1] : 0;
    for (int i = lo; i < hi; ++i) { row_start[i] = run; run += cnt[i]; }
    if (t == 1023) row_start[N] = buf[1023];
}

// ---------------- CSR scatter (dst-sorted src list) ----------------
__global__ void fill_kernel(const int* __restrict__ src, const int* __restrict__ dst,
                            const int* __restrict__ flag,
                            const int* __restrict__ row_start, int* __restrict__ cursor,
                            int* __restrict__ csr_src) {
    int e = blockIdx.x * 256 + threadIdx.x;
    int st = 1 + flag[0];
    if (e < EDGES) {
        int d = dst[e * st];
        int pos = atomicAdd(&cursor[d], 1);
        csr_src[row_start[d] + pos] = src[e * st];
    }
}

// ---------------- PbT[n][k] (bf16): k<K_INC -> (next_h @ (W_fus .* topDown_w))^T;
// ---------------- K_INC..K_TOT -> (W_conv .* conv_w)^T; rest zero ----------------
__global__ __launch_bounds__(128) void p_kernel(
    const float* __restrict__ next_h, const float* __restrict__ W_fus,
    const float* __restrict__ topDown_w, const float* __restrict__ W_conv,
    const float* __restrict__ conv_w, ushort* __restrict__ PbT) {
    int k = blockIdx.x, n = threadIdx.x;
    float v;
    if (k < K_INC) {
        __shared__ float nh[D];
        nh[n] = next_h[k * D + n];
        __syncthreads();
        float acc = 0.f;
        for (int j = 0; j < D; ++j) acc += nh[j] * W_fus[j * D + n];
        v = acc * topDown_w[n];
    } else if (k < K_TOT) {
        v = W_conv[(k - K_INC) * D + n] * conv_w[n];
    } else {
        v = 0.f;
    }
    PbT[(size_t)n * K_PAD + k] = f2bf(v);
}

// ---------------- big GEMM: Zs(bf16) = ([inc | curr_h] @ PbT^T) * norm_out ----------------
// tile 64x128, BK=64, 256 threads (4 waves as 2x2 of 32x64 wave-tiles)
__global__ __launch_bounds__(256) void gemm_kernel(
    const float* __restrict__ inc, const float* __restrict__ curr_h,
    const ushort* __restrict__ PbT, const int* __restrict__ out_deg,
    ushort* __restrict__ Zs) {
    __shared__ ushort As[64][72];    // [m][k] bf16, 64 payload + 8 pad
    __shared__ ushort Bs[128][72];   // [n][k] bf16
    const int N = N_NODES;
    int tid = threadIdx.x;
    int wave = tid >> 6, lane = tid & 63;
    int wm = wave >> 1, wn = wave & 1;
    int r = lane & 15, q = lane >> 4;
    int rowBase = blockIdx.x * 64;

    f32x4 acc[2][4] = {};

    for (int kt = 0; kt < K_PAD / 64; ++kt) {
        int k0 = kt * 64;
        __syncthreads();
        // A: 64 rows x 64 f32 -> bf16. 1024 four-float chunks; 4 per thread
#pragma unroll
        for (int it = 0; it < 4; ++it) {
            int id = tid + it * 256;
            int arow = id >> 4, c4 = id & 15;
            int gk = k0 + c4 * 4;
            int grow = rowBase + arow; if (grow >= N) grow = N - 1;
            float4 va;
            if (gk < K_INC)      va = *(const float4*)(inc + (size_t)grow * K_INC + gk);
            else if (gk < K_TOT) va = *(const float4*)(curr_h + (size_t)grow * D + (gk - K_INC));
            else                 va = make_float4(0.f, 0.f, 0.f, 0.f);
            ushort4 hb;
            hb.x = f2bf(va.x); hb.y = f2bf(va.y); hb.z = f2bf(va.z); hb.w = f2bf(va.w);
            *(ushort4*)&As[arow][c4 * 4] = hb;
        }
        // B: 128 rows x 64 bf16 = 8 x uint4 per row; 1024 chunks; 4 per thread
#pragma unroll
        for (int it = 0; it < 4; ++it) {
            int id = tid + it * 256;
            int brow = id >> 3, c8 = id & 7;
            uint4 vb = *(const uint4*)(PbT + (size_t)brow * K_PAD + k0 + c8 * 8);
            *(uint4*)&Bs[brow][c8 * 8] = vb;
        }
        __syncthreads();
#pragma unroll
        for (int kk = 0; kk < 2; ++kk) {
            short8 af[2], bfr[4];
#pragma unroll
            for (int mi = 0; mi < 2; ++mi)
                af[mi] = *(const short8*)&As[wm * 32 + mi * 16 + r][kk * 32 + q * 8];
#pragma unroll
            for (int ni = 0; ni < 4; ++ni)
                bfr[ni] = *(const short8*)&Bs[wn * 64 + ni * 16 + r][kk * 32 + q * 8];
#pragma unroll
            for (int mi = 0; mi < 2; ++mi)
#pragma unroll
                for (int ni = 0; ni < 4; ++ni)
                    acc[mi][ni] = __builtin_amdgcn_mfma_f32_16x16x32_bf16(af[mi], bfr[ni], acc[mi][ni], 0, 0, 0);
        }
    }

#pragma unroll
    for (int mi = 0; mi < 2; ++mi) {
#pragma unroll
        for (int j = 0; j < 4; ++j) {
            int grow = rowBase + wm * 32 + mi * 16 + q * 4 + j;   // C/D: row = (lane>>4)*4 + reg [m89]
            if (grow < N) {
                float no = rsqrtf((float)(out_deg[grow] + 1));    // +1 self-loop
#pragma unroll
                for (int ni = 0; ni < 4; ++ni) {
                    int col = wn * 64 + ni * 16 + r;              // C/D: col = lane&15 [m89]
                    Zs[(size_t)grow * D + col] = f2bf(acc[mi][ni][j] * no);
                }
            }
        }
    }
}

// ---------------- fused aggregation + norm_in + bias + LayerNorm + ReLU ----------------
// 1 wave per node, 2 channels per lane (uint = bf16x2), 4 nodes per block
__global__ __launch_bounds__(256) void agg_ln_kernel(
    const ushort* __restrict__ Zs, const int* __restrict__ row_start,
    const int* __restrict__ csr_src,
    const float* __restrict__ b_conv, const float* __restrict__ b_fus,
    const float* __restrict__ conv_w, const float* __restrict__ topDown_w,
    const float* __restrict__ gamma, const float* __restrict__ beta,
    float* __restrict__ out) {
    int wid = threadIdx.x >> 6, lane = threadIdx.x & 63;
    int node = blockIdx.x * 4 + wid;
    if (node >= N_NODES) return;
    int c0 = lane * 2;

    uint v = *(const uint*)(Zs + (size_t)node * D + c0);   // self-loop
    float a0 = bf_lo(v), a1 = bf_hi(v);
    int beg = row_start[node], end = row_start[node + 1];
    int e = beg;
    for (; e + 1 < end; e += 2) {
        int s0 = csr_src[e], s1 = csr_src[e + 1];
        uint v0 = *(const uint*)(Zs + (size_t)s0 * D + c0);
        uint v1 = *(const uint*)(Zs + (size_t)s1 * D + c0);
        a0 += bf_lo(v0) + bf_lo(v1);
        a1 += bf_hi(v0) + bf_hi(v1);
    }
    if (e < end) {
        int s0 = csr_src[e];
        uint v0 = *(const uint*)(Zs + (size_t)s0 * D + c0);
        a0 += bf_lo(v0); a1 += bf_hi(v0);
    }
    float nin = rsqrtf((float)(end - beg + 1));
    float y0 = a0 * nin + b_conv[c0] * conv_w[c0] + b_fus[c0] * topDown_w[c0];
    float y1 = a1 * nin + b_conv[c0 + 1] * conv_w[c0 + 1] + b_fus[c0 + 1] * topDown_w[c0 + 1];

    float s1v = y0 + y1, s2v = y0 * y0 + y1 * y1;
#pragma unroll
    for (int off = 1; off < 64; off <<= 1) {
        s1v += __shfl_xor(s1v, off);
        s2v += __shfl_xor(s2v, off);
    }
    float mu = s1v * (1.f / D);
    float var = s2v * (1.f / D) - mu * mu;
    float rstd = rsqrtf(var + LN_EPS);
    float r0 = (y0 - mu) * rstd * gamma[c0] + beta[c0];
    float r1 = (y1 - mu) * rstd * gamma[c0 + 1] + beta[c0 + 1];
    *(float2*)(out + (size_t)node * D + c0) = make_float2(fmaxf(r0, 0.f), fmaxf(r1, 0.f));
}

extern "C" void kernel_launch(void* const* d_in, const int* in_sizes, int n_in,
                              void* d_out, int out_size, void* d_ws, size_t ws_size,
                              hipStream_t stream) {
    const float* curr_h    = (const float*)d_in[0];
    const float* next_h    = (const float*)d_in[1];
    const float* inc       = (const float*)d_in[2];
    const int*   src       = (const int*)d_in[3];
    const int*   dst       = (const int*)d_in[4];
    const float* W_conv    = (const float*)d_in[5];
    const float* b_conv    = (const float*)d_in[6];
    const float* W_fus     = (const float*)d_in[7];
    const float* b_fus     = (const float*)d_in[8];
    const float* conv_w    = (const float*)d_in[9];
    const float* topDown_w = (const float*)d_in[10];
    const float* ln_gamma  = (const float*)d_in[11];
    const float* ln_beta   = (const float*)d_in[12];

    const int N = N_NODES;
    const int E = EDGES;

    // ---- workspace carve ----
    char* p = (char*)d_ws;
    ushort* Zs = (ushort*)p;     p += (size_t)N * D * sizeof(ushort);   // 12.8 MB (bf16)
    ushort* PbT = (ushort*)p;    p += (size_t)D * K_PAD * 2;            // 557 KB
    int* out_deg   = (int*)p;    p += (size_t)N * 4;                    // contiguous: out_deg,in_cnt,cursor
    int* in_cnt    = (int*)p;    p += (size_t)N * 4;
    int* cursor    = (int*)p;    p += (size_t)N * 4;
    int* row_start = (int*)p;    p += (size_t)(N + 1) * 4;
    int* idx_flag  = (int*)p;    p += 256;
    int* csr_src   = (int*)p;    p += (size_t)E * 4;

    probe_kernel<<<1, 1024, 0, stream>>>(src, idx_flag);
    zero_kernel<<<(3 * N + 255) / 256, 256, 0, stream>>>(out_deg, 3 * N);
    deg_kernel<<<(E + 255) / 256, 256, 0, stream>>>(src, dst, idx_flag, out_deg, in_cnt);
    scan_kernel<<<1, 1024, 0, stream>>>(in_cnt, row_start);
    fill_kernel<<<(E + 255) / 256, 256, 0, stream>>>(src, dst, idx_flag, row_start, cursor, csr_src);
    p_kernel<<<K_PAD, 128, 0, stream>>>(next_h, W_fus, topDown_w, W_conv, conv_w, PbT);
    gemm_kernel<<<(N + 63) / 64, 256, 0, stream>>>(inc, curr_h, PbT, out_deg, Zs);
    agg_ln_kernel<<<(N + 3) / 4, 256, 0, stream>>>(Zs, row_start, csr_src,
                                                   b_conv, b_fus, conv_w, topDown_w,
                                                   ln_gamma, ln_beta, (float*)d_out);
}